// Round 1
// baseline (4017.183 us; speedup 1.0000x reference)
//
#include <hip/hip_runtime.h>

// Triplane bilinear sampling.
// Output layout: out[n][c], c = b*32 + ch, b = level*3 + plane, 288 feats/point.
// One thread handles 4 consecutive channels of one (point, grid) pair -> float4 store.
// 72 float4 groups per point; thread id == float4 output index.

struct GridPtrs { const float* g[9]; };

__global__ __launch_bounds__(256) void triplane_sample_kernel(
    const float* __restrict__ pts,
    GridPtrs gp,
    float* __restrict__ out,
    int n_pts)
{
    const int tid = blockIdx.x * 256 + threadIdx.x;
    const int total = n_pts * 72;           // 288 feats / 4 per thread
    if (tid >= total) return;

    const int n  = tid / 72;
    const int c4 = tid - n * 72;            // 0..71
    const int b  = c4 >> 3;                 // grid index 0..8
    const int ch = (c4 & 7) << 2;           // channel start: 0,4,...,28
    const int l  = (b >= 6) ? 2 : (b >= 3 ? 1 : 0);
    const int p  = b - l * 3;               // plane 0,1,2

    // Load point (broadcast across the 72 threads of this point via L1).
    const float vx = pts[n * 3 + 0];
    const float vy = pts[n * 3 + 1];
    const float vz = pts[n * 3 + 2];

    // Exactly the reference arithmetic: (v - BOUNDS) * (2/(-2*BOUNDS)) - 1
    const float scale = 2.0f / (-2.0f * 1.6f);   // -0.625 exactly
    const float px = (vx - 1.6f) * scale - 1.0f;
    const float py = (vy - 1.6f) * scale - 1.0f;
    const float pz = (vz - 1.6f) * scale - 1.0f;

    // plane 0: (y,z)  plane 1: (x,z)  plane 2: (x,y)
    const float cx = (p == 0) ? py : px;
    const float cy = (p == 2) ? py : pz;

    const int   R   = 128 << l;
    const float Rm1 = (float)(R - 1);

    float x = (cx + 1.0f) * 0.5f * Rm1;
    float y = (cy + 1.0f) * 0.5f * Rm1;
    x = fminf(fmaxf(x, 0.0f), Rm1);
    y = fminf(fmaxf(y, 0.0f), Rm1);

    const float x0f = floorf(x);
    const float y0f = floorf(y);
    const float wx  = x - x0f;
    const float wy  = y - y0f;
    const int x0 = (int)x0f;
    const int y0 = (int)y0f;
    const int x1 = min(x0 + 1, R - 1);
    const int y1 = min(y0 + 1, R - 1);

    const size_t RR   = (size_t)R * (size_t)R;
    const float* base = gp.g[b] + (size_t)ch * RR;

    const int i00 = y0 * R + x0;
    const int i01 = y0 * R + x1;
    const int i10 = y1 * R + x0;
    const int i11 = y1 * R + x1;

    const float omwx = 1.0f - wx;
    const float omwy = 1.0f - wy;

    float r[4];
#pragma unroll
    for (int k = 0; k < 4; ++k) {
        const float* gk = base + (size_t)k * RR;
        const float v00 = gk[i00];
        const float v01 = gk[i01];
        const float v10 = gk[i10];
        const float v11 = gk[i11];
        r[k] = (v00 * omwx + v01 * wx) * omwy + (v10 * omwx + v11 * wx) * wy;
    }

    float4* out4 = (float4*)out;
    out4[tid] = make_float4(r[0], r[1], r[2], r[3]);
}

extern "C" void kernel_launch(void* const* d_in, const int* in_sizes, int n_in,
                              void* d_out, int out_size, void* d_ws, size_t ws_size,
                              hipStream_t stream)
{
    const float* pts = (const float*)d_in[0];
    GridPtrs gp;
    for (int i = 0; i < 9; ++i) gp.g[i] = (const float*)d_in[1 + i];
    float* out = (float*)d_out;

    const int n_pts = in_sizes[0] / 3;       // 300000
    const int total = n_pts * 72;            // N * 288 / 4
    const int block = 256;
    const int grid  = (total + block - 1) / block;

    triplane_sample_kernel<<<grid, block, 0, stream>>>(pts, gp, out, n_pts);
}

// Round 2
// 622.020 us; speedup vs baseline: 6.4583x; 6.4583x over previous
//
#include <hip/hip_runtime.h>

// Triplane bilinear sampling, two-phase:
//   Phase 1: transpose each grid (32, R, R) -> (R, R, 32) into d_ws
//            so all 32 channels of one texel are contiguous (128 B).
//   Phase 2: gather. One thread per (point, grid, 4-channel group); the 8
//            threads of one (point,grid) read consecutive 16 B chunks of each
//            128 B corner block -> fully-used cache lines, coalesced f4 store.
//
// Output layout: out[n][c], c = b*32 + ch, b = level*3 + plane.

struct GridPtrs { const float* g[9]; };
struct GridOffs { size_t off[9]; };   // float offsets into transposed ws

// ---------------- Phase 1: transpose ----------------
// gridDim.y = b (0..8). Thread: ch = tid&31, covers 16 consecutive texels.
// Reads: each lane consumes one full 64B line per 16-texel chunk.
// Writes: 32 consecutive lanes write one contiguous 128 B texel block.
__global__ __launch_bounds__(256) void transpose_grids_kernel(
    GridPtrs gp, GridOffs go, float* __restrict__ t)
{
    const int b = blockIdx.y;
    const int l = b / 3;
    const int R = 128 << l;
    const int T = R * R;

    const int tid  = blockIdx.x * 256 + threadIdx.x;
    const int ch   = tid & 31;
    const int t0   = (tid >> 5) * 16;
    if (t0 >= T) return;

    const float* __restrict__ src = gp.g[b] + (size_t)ch * (size_t)T + t0;
    float* __restrict__ dst = t + go.off[b];

#pragma unroll
    for (int i = 0; i < 16; ++i) {
        dst[(size_t)(t0 + i) * 32 + ch] = src[i];
    }
}

// ---------------- Phase 2: gather (transposed grids) ----------------
__global__ __launch_bounds__(256) void triplane_sample_t_kernel(
    const float* __restrict__ pts,
    const float* __restrict__ tg,
    GridOffs go,
    float* __restrict__ out,
    int n_pts)
{
    const int tid = blockIdx.x * 256 + threadIdx.x;
    const int total = n_pts * 72;           // 288 feats / 4 per thread
    if (tid >= total) return;

    const int n  = tid / 72;
    const int c4 = tid - n * 72;            // 0..71
    const int b  = c4 >> 3;                 // grid index 0..8
    const int ch = (c4 & 7) << 2;           // channel start: 0,4,...,28
    const int l  = (b >= 6) ? 2 : (b >= 3 ? 1 : 0);
    const int p  = b - l * 3;               // plane 0,1,2

    const float vx = pts[n * 3 + 0];
    const float vy = pts[n * 3 + 1];
    const float vz = pts[n * 3 + 2];

    // Exactly the reference arithmetic: (v - BOUNDS) * (2/(-2*BOUNDS)) - 1
    const float scale = 2.0f / (-2.0f * 1.6f);   // -0.625
    const float px = (vx - 1.6f) * scale - 1.0f;
    const float py = (vy - 1.6f) * scale - 1.0f;
    const float pz = (vz - 1.6f) * scale - 1.0f;

    // plane 0: (y,z)  plane 1: (x,z)  plane 2: (x,y)
    const float cx = (p == 0) ? py : px;
    const float cy = (p == 2) ? py : pz;

    const int   R   = 128 << l;
    const float Rm1 = (float)(R - 1);

    float x = (cx + 1.0f) * 0.5f * Rm1;
    float y = (cy + 1.0f) * 0.5f * Rm1;
    x = fminf(fmaxf(x, 0.0f), Rm1);
    y = fminf(fmaxf(y, 0.0f), Rm1);

    const float x0f = floorf(x);
    const float y0f = floorf(y);
    const float wx  = x - x0f;
    const float wy  = y - y0f;
    const int x0 = (int)x0f;
    const int y0 = (int)y0f;
    const int x1 = min(x0 + 1, R - 1);
    const int y1 = min(y0 + 1, R - 1);

    const float* base = tg + go.off[b] + ch;
    const size_t s00 = ((size_t)(y0 * R + x0)) * 32;
    const size_t s01 = ((size_t)(y0 * R + x1)) * 32;
    const size_t s10 = ((size_t)(y1 * R + x0)) * 32;
    const size_t s11 = ((size_t)(y1 * R + x1)) * 32;

    const float4 v00 = *(const float4*)(base + s00);
    const float4 v01 = *(const float4*)(base + s01);
    const float4 v10 = *(const float4*)(base + s10);
    const float4 v11 = *(const float4*)(base + s11);

    const float omwx = 1.0f - wx;
    const float omwy = 1.0f - wy;

    float4 r;
    r.x = (v00.x * omwx + v01.x * wx) * omwy + (v10.x * omwx + v11.x * wx) * wy;
    r.y = (v00.y * omwx + v01.y * wx) * omwy + (v10.y * omwx + v11.y * wx) * wy;
    r.z = (v00.z * omwx + v01.z * wx) * omwy + (v10.z * omwx + v11.z * wx) * wy;
    r.w = (v00.w * omwx + v01.w * wx) * omwy + (v10.w * omwx + v11.w * wx) * wy;

    ((float4*)out)[tid] = r;
}

// ---------------- Fallback: direct gather on channel-major grids ----------------
__global__ __launch_bounds__(256) void triplane_sample_kernel(
    const float* __restrict__ pts,
    GridPtrs gp,
    float* __restrict__ out,
    int n_pts)
{
    const int tid = blockIdx.x * 256 + threadIdx.x;
    const int total = n_pts * 72;
    if (tid >= total) return;

    const int n  = tid / 72;
    const int c4 = tid - n * 72;
    const int b  = c4 >> 3;
    const int ch = (c4 & 7) << 2;
    const int l  = (b >= 6) ? 2 : (b >= 3 ? 1 : 0);
    const int p  = b - l * 3;

    const float vx = pts[n * 3 + 0];
    const float vy = pts[n * 3 + 1];
    const float vz = pts[n * 3 + 2];

    const float scale = 2.0f / (-2.0f * 1.6f);
    const float px = (vx - 1.6f) * scale - 1.0f;
    const float py = (vy - 1.6f) * scale - 1.0f;
    const float pz = (vz - 1.6f) * scale - 1.0f;

    const float cx = (p == 0) ? py : px;
    const float cy = (p == 2) ? py : pz;

    const int   R   = 128 << l;
    const float Rm1 = (float)(R - 1);

    float x = (cx + 1.0f) * 0.5f * Rm1;
    float y = (cy + 1.0f) * 0.5f * Rm1;
    x = fminf(fmaxf(x, 0.0f), Rm1);
    y = fminf(fmaxf(y, 0.0f), Rm1);

    const float x0f = floorf(x);
    const float y0f = floorf(y);
    const float wx  = x - x0f;
    const float wy  = y - y0f;
    const int x0 = (int)x0f;
    const int y0 = (int)y0f;
    const int x1 = min(x0 + 1, R - 1);
    const int y1 = min(y0 + 1, R - 1);

    const size_t RR   = (size_t)R * (size_t)R;
    const float* base = gp.g[b] + (size_t)ch * RR;

    const int i00 = y0 * R + x0;
    const int i01 = y0 * R + x1;
    const int i10 = y1 * R + x0;
    const int i11 = y1 * R + x1;

    const float omwx = 1.0f - wx;
    const float omwy = 1.0f - wy;

    float r[4];
#pragma unroll
    for (int k = 0; k < 4; ++k) {
        const float* gk = base + (size_t)k * RR;
        r[k] = (gk[i00] * omwx + gk[i01] * wx) * omwy
             + (gk[i10] * omwx + gk[i11] * wx) * wy;
    }
    ((float4*)out)[tid] = make_float4(r[0], r[1], r[2], r[3]);
}

extern "C" void kernel_launch(void* const* d_in, const int* in_sizes, int n_in,
                              void* d_out, int out_size, void* d_ws, size_t ws_size,
                              hipStream_t stream)
{
    const float* pts = (const float*)d_in[0];
    GridPtrs gp;
    for (int i = 0; i < 9; ++i) gp.g[i] = (const float*)d_in[1 + i];
    float* out = (float*)d_out;

    const int n_pts = in_sizes[0] / 3;       // 300000
    const int total = n_pts * 72;            // N * 288 / 4
    const int block = 256;
    const int grid  = (total + block - 1) / block;

    // Transposed-grid float offsets and total size.
    GridOffs go;
    size_t off = 0;
    for (int b = 0; b < 9; ++b) {
        go.off[b] = off;
        const int R = 128 << (b / 3);
        off += (size_t)32 * R * R;
    }
    const size_t needed_bytes = off * sizeof(float);   // ~132 MB

    if (ws_size >= needed_bytes) {
        float* tg = (float*)d_ws;
        // Phase 1: transpose. Largest grid (R=512): T=262144 texels,
        // threads = 32 * T/16 = 524288 -> 2048 blocks of 256.
        dim3 tgrid(2048, 9, 1);
        transpose_grids_kernel<<<tgrid, block, 0, stream>>>(gp, go, tg);
        // Phase 2: gather from transposed grids.
        triplane_sample_t_kernel<<<grid, block, 0, stream>>>(pts, tg, go, out, n_pts);
    } else {
        triplane_sample_kernel<<<grid, block, 0, stream>>>(pts, gp, out, n_pts);
    }
}